// Round 1
// baseline (681.981 us; speedup 1.0000x reference)
//
#include <hip/hip_runtime.h>

typedef _Float16 f16;
typedef _Float16 f16x8 __attribute__((ext_vector_type(8)));
typedef float f32x4 __attribute__((ext_vector_type(4)));

#define NROWS 32768
#define BR 32
#define TS 28

#define MFMA16(A, B, C) __builtin_amdgcn_mfma_f32_16x16x32_f16((A), (B), (C), 0, 0, 0)

__device__ __forceinline__ f32x4 splat4(float v) { f32x4 r = {v, v, v, v}; return r; }
__device__ __forceinline__ float frcp(float v) { return __builtin_amdgcn_rcpf(v); }
// sigmoid(x) = 1/(1+e^-x); safe for large |x| (e^inf -> rcp -> 0)
__device__ __forceinline__ float fsig(float v) { return frcp(1.f + __expf(-v)); }
// tanh(x) = 1 - 2/(e^{2x}+1); e->0 gives -1, e->inf gives +1 (no NaN)
__device__ __forceinline__ float ftanh(float v) {
  float e = __expf(v + v);
  return 1.f - 2.f * frcp(e + 1.f);
}

// ---------------------------------------------------------------------------
// Prep: f32 weights -> f16 MFMA B-fragments in d_ws.
// Fragment layout for v_mfma_f32_16x16x32_f16 B operand:
//   lane l, elem i -> col n = nt*16 + (l&15), k = kt*32 + (l>>4)*8 + i
// frag index space: wih1: 0..23 (nt, kt=0, K=28 zero-padded to 32)
//                   whh1: 24 + nt*4 + kt   (K=128)
//                   wih2: 120 + nt*4 + kt
//                   whh2: 216 + nt*4 + kt
// each frag = 64 lanes * 8 halves = 1 KiB; total 312 KiB in d_ws.
// ---------------------------------------------------------------------------
__global__ void prep_weights(const float* __restrict__ wih1,
                             const float* __restrict__ whh1,
                             const float* __restrict__ wih2,
                             const float* __restrict__ whh2,
                             f16* __restrict__ wsf) {
  const int f = blockIdx.x;       // 0..311
  const int lane = threadIdx.x;   // 0..63
  const float* src;
  int K, nt, kt;
  if (f < 24)       { src = wih1; K = 28;  nt = f;             kt = 0; }
  else if (f < 120) { src = whh1; K = 128; int i = f - 24;  nt = i >> 2; kt = i & 3; }
  else if (f < 216) { src = wih2; K = 128; int i = f - 120; nt = i >> 2; kt = i & 3; }
  else              { src = whh2; K = 128; int i = f - 216; nt = i >> 2; kt = i & 3; }
  const int n  = nt * 16 + (lane & 15);
  const int k0 = kt * 32 + (lane >> 4) * 8;
  f16x8 pack;
#pragma unroll
  for (int i = 0; i < 8; i++) {
    const int k = k0 + i;
    float v = (k < K) ? src[n * K + k] : 0.f;
    pack[i] = (f16)v;
  }
  ((f16x8*)wsf)[f * 64 + lane] = pack;
}

// ---------------------------------------------------------------------------
// Main: persistent 28-step 2-layer GRU. 8 waves/block, BR=32 rows/block.
// Wave w owns h-dims [16w,16w+16): gate col tiles {w, 8+w, 16+w} (r,z,n).
// Weights live in VGPRs for the whole sequence. h1/h2 exchanged via
// double-buffered XOR-swizzled f16 LDS tiles.
// ---------------------------------------------------------------------------
__global__ __launch_bounds__(512, 2) void gru_main(
    const float* __restrict__ x,
    const float* __restrict__ bih1, const float* __restrict__ bhh1,
    const float* __restrict__ bih2, const float* __restrict__ bhh2,
    const float* __restrict__ wout, const float* __restrict__ bout,
    const f16* __restrict__ wsf,
    float* __restrict__ out) {
  __shared__ __align__(16) f16 h1b[2][BR * 128];
  __shared__ __align__(16) f16 h2b[2][BR * 128];

  const int tid  = threadIdx.x;
  const int wv   = tid >> 6;    // wave 0..7
  const int lane = tid & 63;
  const int lr   = lane & 15;   // A-row / B-col / D-col index
  const int kg   = lane >> 4;   // k-group (A/B) and D row-group
  const int row0 = blockIdx.x * BR;
  const int d    = wv * 16 + lr;  // this lane's h-dim (gate column)

  // zero-init LDS state buffers (h=0 at t=0)
  {
    unsigned int* z1 = (unsigned int*)&h1b[0][0];
    unsigned int* z2 = (unsigned int*)&h2b[0][0];
#pragma unroll
    for (int i = 0; i < 8; i++) { z1[tid + 512 * i] = 0u; z2[tid + 512 * i] = 0u; }
  }

  // weight fragments -> registers (persist across all 28 steps)
  const f16x8* wf = (const f16x8*)wsf;
  f16x8 Wih1[3], Whh1[3][4], Wih2[3][4], Whh2[3][4];
#pragma unroll
  for (int g = 0; g < 3; g++) {   // g: 0=r,1=z,2=n
    const int nt = wv + g * 8;
    Wih1[g] = wf[nt * 64 + lane];
#pragma unroll
    for (int kt = 0; kt < 4; kt++) {
      Whh1[g][kt] = wf[(24  + nt * 4 + kt) * 64 + lane];
      Wih2[g][kt] = wf[(120 + nt * 4 + kt) * 64 + lane];
      Whh2[g][kt] = wf[(216 + nt * 4 + kt) * 64 + lane];
    }
  }

  // biases for this lane's gate column d
  const float b1r = bih1[d] + bhh1[d];
  const float b1z = bih1[128 + d] + bhh1[128 + d];
  const float b1i = bih1[256 + d];          // i_n bias (stays separate: r * h_n)
  const float b1h = bhh1[256 + d];          // h_n bias
  const float b2r = bih2[d] + bhh2[d];
  const float b2z = bih2[128 + d] + bhh2[128 + d];
  const float b2i = bih2[256 + d];
  const float b2h = bhh2[256 + d];

  // carried h state (f32, 8 (row,dim) pairs per lane per layer)
  float h1s[2][4] = {{0, 0, 0, 0}, {0, 0, 0, 0}};
  float h2s[2][4] = {{0, 0, 0, 0}, {0, 0, 0, 0}};

  __syncthreads();

  for (int t = 0; t < TS; t++) {
    const int cur = t & 1, nxt = cur ^ 1;
    f32x4 aR[2], aZ[2], aI[2], aH[2];
#pragma unroll
    for (int rt = 0; rt < 2; rt++) {
      aR[rt] = splat4(b1r); aZ[rt] = splat4(b1z);
      aI[rt] = splat4(b1i); aH[rt] = splat4(b1h);
    }
    // x A-fragments straight from global (L2/L3-resident working set)
    f16x8 ax[2];
#pragma unroll
    for (int rt = 0; rt < 2; rt++) {
      const float* xp = x + (size_t)(row0 + rt * 16 + lr) * 784 + t * 28 + kg * 8;
      float4 p0 = *(const float4*)xp;               // k0..k0+3 (always < 28)
      float4 p1 = {0.f, 0.f, 0.f, 0.f};
      if (kg < 3) p1 = *(const float4*)(xp + 4);    // kg==3: k=28..31 zero pad
      ax[rt][0] = (f16)p0.x; ax[rt][1] = (f16)p0.y;
      ax[rt][2] = (f16)p0.z; ax[rt][3] = (f16)p0.w;
      ax[rt][4] = (f16)p1.x; ax[rt][5] = (f16)p1.y;
      ax[rt][6] = (f16)p1.z; ax[rt][7] = (f16)p1.w;
    }
    // ---- layer-1 gates: acc = bias + x@Wih1^T + h1@Whh1^T
#pragma unroll
    for (int rt = 0; rt < 2; rt++) {
      const int r = rt * 16 + lr;
      const int sw = (r & 7) << 3;   // XOR swizzle (half-index) vs bank conflicts
#pragma unroll
      for (int kt = 0; kt < 4; kt++) {
        f16x8 a = *(const f16x8*)&h1b[cur][(r * 128 + kt * 32 + kg * 8) ^ sw];
        aR[rt] = MFMA16(a, Whh1[0][kt], aR[rt]);
        aZ[rt] = MFMA16(a, Whh1[1][kt], aZ[rt]);
        aH[rt] = MFMA16(a, Whh1[2][kt], aH[rt]);
      }
      aR[rt] = MFMA16(ax[rt], Wih1[0], aR[rt]);
      aZ[rt] = MFMA16(ax[rt], Wih1[1], aZ[rt]);
      aI[rt] = MFMA16(ax[rt], Wih1[2], aI[rt]);
    }
    // ---- layer-1 elementwise: D lane map col=lane&15(=d), row=kg*4+i
#pragma unroll
    for (int rt = 0; rt < 2; rt++) {
#pragma unroll
      for (int i = 0; i < 4; i++) {
        float rg = fsig(aR[rt][i]);
        float zg = fsig(aZ[rt][i]);
        float nn = ftanh(fmaf(rg, aH[rt][i], aI[rt][i]));
        float hp = h1s[rt][i];
        float hn = fmaxf(fmaf(zg, hp - nn, nn), 0.f);   // relu((1-z)n+zh)
        h1s[rt][i] = hn;
        const int rr = rt * 16 + kg * 4 + i;
        h1b[nxt][(rr * 128 + d) ^ ((rr & 7) << 3)] = (f16)hn;
      }
    }
    __syncthreads();
    // ---- layer-2 gates: acc = bias + h1_new@Wih2^T + h2@Whh2^T
#pragma unroll
    for (int rt = 0; rt < 2; rt++) {
      aR[rt] = splat4(b2r); aZ[rt] = splat4(b2z);
      aI[rt] = splat4(b2i); aH[rt] = splat4(b2h);
    }
#pragma unroll
    for (int rt = 0; rt < 2; rt++) {
      const int r = rt * 16 + lr;
      const int sw = (r & 7) << 3;
#pragma unroll
      for (int kt = 0; kt < 4; kt++) {
        f16x8 a1 = *(const f16x8*)&h1b[nxt][(r * 128 + kt * 32 + kg * 8) ^ sw];
        f16x8 a2 = *(const f16x8*)&h2b[cur][(r * 128 + kt * 32 + kg * 8) ^ sw];
        aR[rt] = MFMA16(a1, Wih2[0][kt], aR[rt]);
        aZ[rt] = MFMA16(a1, Wih2[1][kt], aZ[rt]);
        aI[rt] = MFMA16(a1, Wih2[2][kt], aI[rt]);
        aR[rt] = MFMA16(a2, Whh2[0][kt], aR[rt]);
        aZ[rt] = MFMA16(a2, Whh2[1][kt], aZ[rt]);
        aH[rt] = MFMA16(a2, Whh2[2][kt], aH[rt]);
      }
    }
#pragma unroll
    for (int rt = 0; rt < 2; rt++) {
#pragma unroll
      for (int i = 0; i < 4; i++) {
        float rg = fsig(aR[rt][i]);
        float zg = fsig(aZ[rt][i]);
        float nn = ftanh(fmaf(rg, aH[rt][i], aI[rt][i]));
        float hp = h2s[rt][i];
        float hn = fmaxf(fmaf(zg, hp - nn, nn), 0.f);
        h2s[rt][i] = hn;
        const int rr = rt * 16 + kg * 4 + i;
        h2b[nxt][(rr * 128 + d) ^ ((rr & 7) << 3)] = (f16)hn;
      }
    }
    __syncthreads();
  }

  // ---- epilogue: out[row,col] = h2 . wout[col,:] + bout[col]
  // TS=28 even -> final h2 lives in h2b[0]
  const int orow = tid >> 4;   // 0..31
  const int ocol = tid & 15;   // 0..15, active < 10
  if (ocol < 10) {
    const f16* hb = h2b[0];
    float s = bout[ocol];
#pragma unroll 8
    for (int k = 0; k < 128; k++) {
      float hv = (float)hb[(orow * 128 + k) ^ ((orow & 7) << 3)];
      s = fmaf(hv, wout[ocol * 128 + k], s);
    }
    out[(size_t)(row0 + orow) * 10 + ocol] = s;
  }
}

extern "C" void kernel_launch(void* const* d_in, const int* in_sizes, int n_in,
                              void* d_out, int out_size, void* d_ws, size_t ws_size,
                              hipStream_t stream) {
  const float* x    = (const float*)d_in[0];
  const float* wih1 = (const float*)d_in[1];
  const float* whh1 = (const float*)d_in[2];
  const float* bih1 = (const float*)d_in[3];
  const float* bhh1 = (const float*)d_in[4];
  const float* wih2 = (const float*)d_in[5];
  const float* whh2 = (const float*)d_in[6];
  const float* bih2 = (const float*)d_in[7];
  const float* bhh2 = (const float*)d_in[8];
  const float* wout = (const float*)d_in[9];
  const float* bout = (const float*)d_in[10];
  f16* wsf   = (f16*)d_ws;
  float* out = (float*)d_out;

  prep_weights<<<312, 64, 0, stream>>>(wih1, whh1, wih2, whh2, wsf);
  gru_main<<<NROWS / BR, 512, 0, stream>>>(x, bih1, bhh1, bih2, bhh2,
                                           wout, bout, wsf, out);
}

// Round 2
// 681.348 us; speedup vs baseline: 1.0009x; 1.0009x over previous
//
#include <hip/hip_runtime.h>

typedef _Float16 f16;
typedef _Float16 f16x8 __attribute__((ext_vector_type(8)));
typedef float f32x4 __attribute__((ext_vector_type(4)));

#define NROWS 32768
#define BR 32
#define TS 28

#define MFMA16(A, B, C) __builtin_amdgcn_mfma_f32_16x16x32_f16((A), (B), (C), 0, 0, 0)

__device__ __forceinline__ f32x4 splat4(float v) { f32x4 r = {v, v, v, v}; return r; }
__device__ __forceinline__ float frcp(float v) { return __builtin_amdgcn_rcpf(v); }
// sigmoid(x) = 1/(1+e^-x); safe for large |x| (e^inf -> rcp -> 0)
__device__ __forceinline__ float fsig(float v) { return frcp(1.f + __expf(-v)); }
// tanh(x) = 1 - 2/(e^{2x}+1); e->0 gives -1, e->inf gives +1 (no NaN)
__device__ __forceinline__ float ftanh(float v) {
  float e = __expf(v + v);
  return 1.f - 2.f * frcp(e + 1.f);
}

// ---------------------------------------------------------------------------
// Prep: f32 weights -> f16 MFMA B-fragments in d_ws.
// Fragment layout for v_mfma_f32_16x16x32_f16 B operand:
//   lane l, elem i -> col n = nt*16 + (l&15), k = kt*32 + (l>>4)*8 + i
// frag index space: wih1: 0..23 (nt, kt=0, K=28 zero-padded to 32)
//                   whh1: 24 + nt*4 + kt   (K=128)
//                   wih2: 120 + nt*4 + kt
//                   whh2: 216 + nt*4 + kt
// each frag = 64 lanes * 8 halves = 1 KiB; total 312 KiB in d_ws.
// ---------------------------------------------------------------------------
__global__ void prep_weights(const float* __restrict__ wih1,
                             const float* __restrict__ whh1,
                             const float* __restrict__ wih2,
                             const float* __restrict__ whh2,
                             f16* __restrict__ wsf) {
  const int f = blockIdx.x;       // 0..311
  const int lane = threadIdx.x;   // 0..63
  const float* src;
  int K, nt, kt;
  if (f < 24)       { src = wih1; K = 28;  nt = f;             kt = 0; }
  else if (f < 120) { src = whh1; K = 128; int i = f - 24;  nt = i >> 2; kt = i & 3; }
  else if (f < 216) { src = wih2; K = 128; int i = f - 120; nt = i >> 2; kt = i & 3; }
  else              { src = whh2; K = 128; int i = f - 216; nt = i >> 2; kt = i & 3; }
  const int n  = nt * 16 + (lane & 15);
  const int k0 = kt * 32 + (lane >> 4) * 8;
  f16x8 pack;
#pragma unroll
  for (int i = 0; i < 8; i++) {
    const int k = k0 + i;
    float v = (k < K) ? src[n * K + k] : 0.f;
    pack[i] = (f16)v;
  }
  ((f16x8*)wsf)[f * 64 + lane] = pack;
}

// ---------------------------------------------------------------------------
// Main: persistent 28-step 2-layer GRU. 8 waves/block, BR=32 rows/block.
// Wave w owns h-dims [16w,16w+16): gate col tiles {w, 8+w, 16+w} (r,z,n).
// Weights live in VGPRs for the whole sequence (156 VGPR/wave) — requires
// the full 256-VGPR budget: __launch_bounds__(512,1). With (512,2) the
// allocator capped at 128 VGPRs and spilled the weight set to scratch
// (R1: WRITE_SIZE 28 MB vs 1.3 MB of real output).
// h1/h2 exchanged via double-buffered XOR-swizzled f16 LDS tiles.
// ---------------------------------------------------------------------------
__global__ __launch_bounds__(512, 1) void gru_main(
    const float* __restrict__ x,
    const float* __restrict__ bih1, const float* __restrict__ bhh1,
    const float* __restrict__ bih2, const float* __restrict__ bhh2,
    const float* __restrict__ wout, const float* __restrict__ bout,
    const f16* __restrict__ wsf,
    float* __restrict__ out) {
  __shared__ __align__(16) f16 h1b[2][BR * 128];
  __shared__ __align__(16) f16 h2b[2][BR * 128];

  const int tid  = threadIdx.x;
  const int wv   = tid >> 6;    // wave 0..7
  const int lane = tid & 63;
  const int lr   = lane & 15;   // A-row / B-col / D-col index
  const int kg   = lane >> 4;   // k-group (A/B) and D row-group
  const int row0 = blockIdx.x * BR;
  const int d    = wv * 16 + lr;  // this lane's h-dim (gate column)

  // zero-init LDS state buffers (h=0 at t=0)
  {
    unsigned int* z1 = (unsigned int*)&h1b[0][0];
    unsigned int* z2 = (unsigned int*)&h2b[0][0];
#pragma unroll
    for (int i = 0; i < 8; i++) { z1[tid + 512 * i] = 0u; z2[tid + 512 * i] = 0u; }
  }

  // weight fragments -> registers (persist across all 28 steps)
  const f16x8* wf = (const f16x8*)wsf;
  f16x8 Wih1[3], Whh1[3][4], Wih2[3][4], Whh2[3][4];
#pragma unroll
  for (int g = 0; g < 3; g++) {   // g: 0=r,1=z,2=n
    const int nt = wv + g * 8;
    Wih1[g] = wf[nt * 64 + lane];
#pragma unroll
    for (int kt = 0; kt < 4; kt++) {
      Whh1[g][kt] = wf[(24  + nt * 4 + kt) * 64 + lane];
      Wih2[g][kt] = wf[(120 + nt * 4 + kt) * 64 + lane];
      Whh2[g][kt] = wf[(216 + nt * 4 + kt) * 64 + lane];
    }
  }

  // biases for this lane's gate column d
  const float b1r = bih1[d] + bhh1[d];
  const float b1z = bih1[128 + d] + bhh1[128 + d];
  const float b1i = bih1[256 + d];          // i_n bias (stays separate: r * h_n)
  const float b1h = bhh1[256 + d];          // h_n bias
  const float b2r = bih2[d] + bhh2[d];
  const float b2z = bih2[128 + d] + bhh2[128 + d];
  const float b2i = bih2[256 + d];
  const float b2h = bhh2[256 + d];

  // carried h state (f32, 8 (row,dim) pairs per lane per layer)
  float h1s[2][4] = {{0, 0, 0, 0}, {0, 0, 0, 0}};
  float h2s[2][4] = {{0, 0, 0, 0}, {0, 0, 0, 0}};

  __syncthreads();

  for (int t = 0; t < TS; t++) {
    const int cur = t & 1, nxt = cur ^ 1;
    f32x4 aR[2], aZ[2], aI[2], aH[2];
#pragma unroll
    for (int rt = 0; rt < 2; rt++) {
      aR[rt] = splat4(b1r); aZ[rt] = splat4(b1z);
      aI[rt] = splat4(b1i); aH[rt] = splat4(b1h);
    }
    // x A-fragments straight from global (L2/L3-resident working set)
    f16x8 ax[2];
#pragma unroll
    for (int rt = 0; rt < 2; rt++) {
      const float* xp = x + (size_t)(row0 + rt * 16 + lr) * 784 + t * 28 + kg * 8;
      float4 p0 = *(const float4*)xp;               // k0..k0+3 (always < 28)
      float4 p1 = {0.f, 0.f, 0.f, 0.f};
      if (kg < 3) p1 = *(const float4*)(xp + 4);    // kg==3: k=28..31 zero pad
      ax[rt][0] = (f16)p0.x; ax[rt][1] = (f16)p0.y;
      ax[rt][2] = (f16)p0.z; ax[rt][3] = (f16)p0.w;
      ax[rt][4] = (f16)p1.x; ax[rt][5] = (f16)p1.y;
      ax[rt][6] = (f16)p1.z; ax[rt][7] = (f16)p1.w;
    }
    // ---- layer-1 gates: acc = bias + x@Wih1^T + h1@Whh1^T
#pragma unroll
    for (int rt = 0; rt < 2; rt++) {
      const int r = rt * 16 + lr;
      const int sw = (r & 7) << 3;   // XOR swizzle (half-index) vs bank conflicts
#pragma unroll
      for (int kt = 0; kt < 4; kt++) {
        f16x8 a = *(const f16x8*)&h1b[cur][(r * 128 + kt * 32 + kg * 8) ^ sw];
        aR[rt] = MFMA16(a, Whh1[0][kt], aR[rt]);
        aZ[rt] = MFMA16(a, Whh1[1][kt], aZ[rt]);
        aH[rt] = MFMA16(a, Whh1[2][kt], aH[rt]);
      }
      aR[rt] = MFMA16(ax[rt], Wih1[0], aR[rt]);
      aZ[rt] = MFMA16(ax[rt], Wih1[1], aZ[rt]);
      aI[rt] = MFMA16(ax[rt], Wih1[2], aI[rt]);
    }
    // ---- layer-1 elementwise: D lane map col=lane&15(=d), row=kg*4+i
#pragma unroll
    for (int rt = 0; rt < 2; rt++) {
#pragma unroll
      for (int i = 0; i < 4; i++) {
        float rg = fsig(aR[rt][i]);
        float zg = fsig(aZ[rt][i]);
        float nn = ftanh(fmaf(rg, aH[rt][i], aI[rt][i]));
        float hp = h1s[rt][i];
        float hn = fmaxf(fmaf(zg, hp - nn, nn), 0.f);   // relu((1-z)n+zh)
        h1s[rt][i] = hn;
        const int rr = rt * 16 + kg * 4 + i;
        h1b[nxt][(rr * 128 + d) ^ ((rr & 7) << 3)] = (f16)hn;
      }
    }
    __syncthreads();
    // ---- layer-2 gates: acc = bias + h1_new@Wih2^T + h2@Whh2^T
#pragma unroll
    for (int rt = 0; rt < 2; rt++) {
      aR[rt] = splat4(b2r); aZ[rt] = splat4(b2z);
      aI[rt] = splat4(b2i); aH[rt] = splat4(b2h);
    }
#pragma unroll
    for (int rt = 0; rt < 2; rt++) {
      const int r = rt * 16 + lr;
      const int sw = (r & 7) << 3;
#pragma unroll
      for (int kt = 0; kt < 4; kt++) {
        f16x8 a1 = *(const f16x8*)&h1b[nxt][(r * 128 + kt * 32 + kg * 8) ^ sw];
        f16x8 a2 = *(const f16x8*)&h2b[cur][(r * 128 + kt * 32 + kg * 8) ^ sw];
        aR[rt] = MFMA16(a1, Wih2[0][kt], aR[rt]);
        aZ[rt] = MFMA16(a1, Wih2[1][kt], aZ[rt]);
        aI[rt] = MFMA16(a1, Wih2[2][kt], aI[rt]);
        aR[rt] = MFMA16(a2, Whh2[0][kt], aR[rt]);
        aZ[rt] = MFMA16(a2, Whh2[1][kt], aZ[rt]);
        aH[rt] = MFMA16(a2, Whh2[2][kt], aH[rt]);
      }
    }
#pragma unroll
    for (int rt = 0; rt < 2; rt++) {
#pragma unroll
      for (int i = 0; i < 4; i++) {
        float rg = fsig(aR[rt][i]);
        float zg = fsig(aZ[rt][i]);
        float nn = ftanh(fmaf(rg, aH[rt][i], aI[rt][i]));
        float hp = h2s[rt][i];
        float hn = fmaxf(fmaf(zg, hp - nn, nn), 0.f);
        h2s[rt][i] = hn;
        const int rr = rt * 16 + kg * 4 + i;
        h2b[nxt][(rr * 128 + d) ^ ((rr & 7) << 3)] = (f16)hn;
      }
    }
    __syncthreads();
  }

  // ---- epilogue: out[row,col] = h2 . wout[col,:] + bout[col]
  // TS=28 even -> final h2 lives in h2b[0]
  const int orow = tid >> 4;   // 0..31
  const int ocol = tid & 15;   // 0..15, active < 10
  if (ocol < 10) {
    const f16* hb = h2b[0];
    float s = bout[ocol];
#pragma unroll 8
    for (int k = 0; k < 128; k++) {
      float hv = (float)hb[(orow * 128 + k) ^ ((orow & 7) << 3)];
      s = fmaf(hv, wout[ocol * 128 + k], s);
    }
    out[(size_t)(row0 + orow) * 10 + ocol] = s;
  }
}

extern "C" void kernel_launch(void* const* d_in, const int* in_sizes, int n_in,
                              void* d_out, int out_size, void* d_ws, size_t ws_size,
                              hipStream_t stream) {
  const float* x    = (const float*)d_in[0];
  const float* wih1 = (const float*)d_in[1];
  const float* whh1 = (const float*)d_in[2];
  const float* bih1 = (const float*)d_in[3];
  const float* bhh1 = (const float*)d_in[4];
  const float* wih2 = (const float*)d_in[5];
  const float* whh2 = (const float*)d_in[6];
  const float* bih2 = (const float*)d_in[7];
  const float* bhh2 = (const float*)d_in[8];
  const float* wout = (const float*)d_in[9];
  const float* bout = (const float*)d_in[10];
  f16* wsf   = (f16*)d_ws;
  float* out = (float*)d_out;

  prep_weights<<<312, 64, 0, stream>>>(wih1, whh1, wih2, whh2, wsf);
  gru_main<<<NROWS / BR, 512, 0, stream>>>(x, bih1, bhh1, bih2, bhh2,
                                           wout, bout, wsf, out);
}

// Round 3
// 615.306 us; speedup vs baseline: 1.1084x; 1.1073x over previous
//
#include <hip/hip_runtime.h>

typedef _Float16 f16;
typedef _Float16 f16x8 __attribute__((ext_vector_type(8)));
typedef float f32x4 __attribute__((ext_vector_type(4)));

#define NROWS 32768
#define BR 32
#define TS 28

#define MFMA16(A, B, C) __builtin_amdgcn_mfma_f32_16x16x32_f16((A), (B), (C), 0, 0, 0)
// pin a loaded value as an opaque register value: compiler can't rematerialize
// the load inside the loop or sink it (R1/R2: weight set silently demoted).
#define KEEP(v) asm volatile("" : "+v"(v))

__device__ __forceinline__ f32x4 splat4(float v) { f32x4 r = {v, v, v, v}; return r; }
__device__ __forceinline__ float frcp(float v) { return __builtin_amdgcn_rcpf(v); }
__device__ __forceinline__ float fsig(float v) { return frcp(1.f + __expf(-v)); }
__device__ __forceinline__ float ftanh(float v) {
  float e = __expf(v + v);
  return 1.f - 2.f * frcp(e + 1.f);
}

// ---------------------------------------------------------------------------
// Prep: f32 weights -> f16 MFMA B-fragments in d_ws.
//   lane l, elem i -> col n = nt*16 + (l&15), k = kt*32 + (l>>4)*8 + i
// frag index space: wih1: 0..23 (K=28 zero-padded to 32)
//                   whh1: 24 + nt*4 + kt
//                   wih2: 120 + nt*4 + kt
//                   whh2: 216 + nt*4 + kt
// ---------------------------------------------------------------------------
__global__ void prep_weights(const float* __restrict__ wih1,
                             const float* __restrict__ whh1,
                             const float* __restrict__ wih2,
                             const float* __restrict__ whh2,
                             f16* __restrict__ wsf) {
  const int f = blockIdx.x;       // 0..311
  const int lane = threadIdx.x;   // 0..63
  const float* src;
  int K, nt, kt;
  if (f < 24)       { src = wih1; K = 28;  nt = f;             kt = 0; }
  else if (f < 120) { src = whh1; K = 128; int i = f - 24;  nt = i >> 2; kt = i & 3; }
  else if (f < 216) { src = wih2; K = 128; int i = f - 120; nt = i >> 2; kt = i & 3; }
  else              { src = whh2; K = 128; int i = f - 216; nt = i >> 2; kt = i & 3; }
  const int n  = nt * 16 + (lane & 15);
  const int k0 = kt * 32 + (lane >> 4) * 8;
  f16x8 pack;
#pragma unroll
  for (int i = 0; i < 8; i++) {
    const int k = k0 + i;
    float v = (k < K) ? src[n * K + k] : 0.f;
    pack[i] = (f16)v;
  }
  ((f16x8*)wsf)[f * 64 + lane] = pack;
}

// ---------------------------------------------------------------------------
// Main: persistent 28-step 2-layer GRU. 8 waves/block, BR=32 rows/block.
// Wave w owns h-dims [16w,16w+16): gate col tiles {w, 8+w, 16+w} (r,z,n).
// Register budget at 1 block/CU (2 waves/SIMD) is 256 combined regs/wave;
// R1/R2 demand (~240) sat at the edge -> 27 MB of scratch spill. Fix:
// Whh1 lives in LDS (96 KB; total LDS 128 KB), cutting demand to ~195.
// Layer-2 weights (Wih2, Whh2) + Wih1 stay in registers, KEEP-pinned.
// h1/h2 exchanged via double-buffered XOR-swizzled f16 LDS tiles.
// x fragments for step t+1 prefetched during layer-2 compute.
// ---------------------------------------------------------------------------
__global__ __launch_bounds__(512, 2) void gru_main(
    const float* __restrict__ x,
    const float* __restrict__ bih1, const float* __restrict__ bhh1,
    const float* __restrict__ bih2, const float* __restrict__ bhh2,
    const float* __restrict__ wout, const float* __restrict__ bout,
    const f16* __restrict__ wsf,
    float* __restrict__ out) {
  __shared__ __align__(16) f16 h1b[2][BR * 128];
  __shared__ __align__(16) f16 h2b[2][BR * 128];
  __shared__ __align__(16) f16 wsh[96 * 512];   // Whh1: 96 frags x 1 KiB = 96 KiB

  const int tid  = threadIdx.x;
  const int wv   = tid >> 6;    // wave 0..7
  const int lane = tid & 63;
  const int lr   = lane & 15;   // A-row / B-col / D-col index
  const int kg   = lane >> 4;   // k-group (A/B) and D row-group
  const int row0 = blockIdx.x * BR;
  const int d    = wv * 16 + lr;  // this lane's h-dim (gate column)
  const int sw   = (lr & 7) << 3; // XOR swizzle (half units); rt*16 = 0 mod 8

  const f16x8* wf = (const f16x8*)wsf;

  // stage Whh1 -> LDS; zero-init h state buffers (h=0 at t=0)
  {
    f16x8* wd = (f16x8*)wsh;
    const f16x8* wsrc = wf + 24 * 64;
#pragma unroll
    for (int i = 0; i < 12; i++) wd[tid + 512 * i] = wsrc[tid + 512 * i];
    unsigned int* z1 = (unsigned int*)&h1b[0][0];
    unsigned int* z2 = (unsigned int*)&h2b[0][0];
#pragma unroll
    for (int i = 0; i < 8; i++) { z1[tid + 512 * i] = 0u; z2[tid + 512 * i] = 0u; }
  }

  // register-resident weights: Wih1 (12 VGPR), Wih2 + Whh2 (96 VGPR)
  f16x8 Wih1[3], Wih2[3][4], Whh2[3][4];
#pragma unroll
  for (int g = 0; g < 3; g++) {
    const int nt = wv + g * 8;
    Wih1[g] = wf[nt * 64 + lane];
    KEEP(Wih1[g]);
#pragma unroll
    for (int kt = 0; kt < 4; kt++) {
      Wih2[g][kt] = wf[(120 + nt * 4 + kt) * 64 + lane];
      KEEP(Wih2[g][kt]);
      Whh2[g][kt] = wf[(216 + nt * 4 + kt) * 64 + lane];
      KEEP(Whh2[g][kt]);
    }
  }

  // biases for this lane's gate column d
  const float b1r = bih1[d] + bhh1[d];
  const float b1z = bih1[128 + d] + bhh1[128 + d];
  const float b1i = bih1[256 + d];
  const float b1h = bhh1[256 + d];
  const float b2r = bih2[d] + bhh2[d];
  const float b2z = bih2[128 + d] + bhh2[128 + d];
  const float b2i = bih2[256 + d];
  const float b2h = bhh2[256 + d];

  // carried h state (f32)
  float h1s[2][4] = {{0, 0, 0, 0}, {0, 0, 0, 0}};
  float h2s[2][4] = {{0, 0, 0, 0}, {0, 0, 0, 0}};

  // x A-fragment loader (28 floats of row, f16-packed, zero-padded to K=32)
  auto load_ax = [&](int t, f16x8* axv) {
#pragma unroll
    for (int rt = 0; rt < 2; rt++) {
      const float* xp = x + (size_t)(row0 + rt * 16 + lr) * 784 + t * 28 + kg * 8;
      float4 p0 = *(const float4*)xp;
      float4 p1 = {0.f, 0.f, 0.f, 0.f};
      if (kg < 3) p1 = *(const float4*)(xp + 4);
      f16x8 a;
      a[0] = (f16)p0.x; a[1] = (f16)p0.y; a[2] = (f16)p0.z; a[3] = (f16)p0.w;
      a[4] = (f16)p1.x; a[5] = (f16)p1.y; a[6] = (f16)p1.z; a[7] = (f16)p1.w;
      axv[rt] = a;
    }
  };

  f16x8 axc[2], axn[2];
  load_ax(0, axc);

  __syncthreads();

  const f16x8* wlds = (const f16x8*)wsh;

  for (int t = 0; t < TS; t++) {
    const int cur = t & 1, nxt = cur ^ 1;
    f32x4 aR[2], aZ[2], aI[2], aH[2];
#pragma unroll
    for (int rt = 0; rt < 2; rt++) {
      aR[rt] = splat4(b1r); aZ[rt] = splat4(b1z);
      aI[rt] = splat4(b1i); aH[rt] = splat4(b1h);
    }
    // ---- layer-1 gates: kt-outer so only 3 Whh1 frags are live at a time
#pragma unroll
    for (int kt = 0; kt < 4; kt++) {
      f16x8 a0 = *(const f16x8*)&h1b[cur][(lr * 128 + kt * 32 + kg * 8) ^ sw];
      f16x8 a1 = *(const f16x8*)&h1b[cur][((16 + lr) * 128 + kt * 32 + kg * 8) ^ sw];
      f16x8 w0 = wlds[((wv     ) * 4 + kt) * 64 + lane];
      f16x8 w1 = wlds[((wv +  8) * 4 + kt) * 64 + lane];
      f16x8 w2 = wlds[((wv + 16) * 4 + kt) * 64 + lane];
      aR[0] = MFMA16(a0, w0, aR[0]); aR[1] = MFMA16(a1, w0, aR[1]);
      aZ[0] = MFMA16(a0, w1, aZ[0]); aZ[1] = MFMA16(a1, w1, aZ[1]);
      aH[0] = MFMA16(a0, w2, aH[0]); aH[1] = MFMA16(a1, w2, aH[1]);
    }
    aR[0] = MFMA16(axc[0], Wih1[0], aR[0]); aR[1] = MFMA16(axc[1], Wih1[0], aR[1]);
    aZ[0] = MFMA16(axc[0], Wih1[1], aZ[0]); aZ[1] = MFMA16(axc[1], Wih1[1], aZ[1]);
    aI[0] = MFMA16(axc[0], Wih1[2], aI[0]); aI[1] = MFMA16(axc[1], Wih1[2], aI[1]);

    // ---- layer-1 elementwise: D lane map col=lane&15(=d), row=kg*4+i
#pragma unroll
    for (int rt = 0; rt < 2; rt++) {
#pragma unroll
      for (int i = 0; i < 4; i++) {
        float rg = fsig(aR[rt][i]);
        float zg = fsig(aZ[rt][i]);
        float nn = ftanh(fmaf(rg, aH[rt][i], aI[rt][i]));
        float hp = h1s[rt][i];
        float hn = fmaxf(fmaf(zg, hp - nn, nn), 0.f);   // relu((1-z)n+zh)
        h1s[rt][i] = hn;
        const int rr = rt * 16 + kg * 4 + i;
        h1b[nxt][(rr * 128 + d) ^ ((rr & 7) << 3)] = (f16)hn;
      }
    }
    __syncthreads();

    // prefetch next step's x fragments; loads overlap layer-2 compute
    load_ax(t + 1 < TS ? t + 1 : t, axn);

    // ---- layer-2 gates: acc = bias + h1_new@Wih2^T + h2@Whh2^T
#pragma unroll
    for (int rt = 0; rt < 2; rt++) {
      aR[rt] = splat4(b2r); aZ[rt] = splat4(b2z);
      aI[rt] = splat4(b2i); aH[rt] = splat4(b2h);
    }
#pragma unroll
    for (int rt = 0; rt < 2; rt++) {
#pragma unroll
      for (int kt = 0; kt < 4; kt++) {
        f16x8 a1 = *(const f16x8*)&h1b[nxt][((rt * 16 + lr) * 128 + kt * 32 + kg * 8) ^ sw];
        f16x8 a2 = *(const f16x8*)&h2b[cur][((rt * 16 + lr) * 128 + kt * 32 + kg * 8) ^ sw];
        aR[rt] = MFMA16(a1, Wih2[0][kt], aR[rt]);
        aZ[rt] = MFMA16(a1, Wih2[1][kt], aZ[rt]);
        aI[rt] = MFMA16(a1, Wih2[2][kt], aI[rt]);
        aR[rt] = MFMA16(a2, Whh2[0][kt], aR[rt]);
        aZ[rt] = MFMA16(a2, Whh2[1][kt], aZ[rt]);
        aH[rt] = MFMA16(a2, Whh2[2][kt], aH[rt]);
      }
    }
#pragma unroll
    for (int rt = 0; rt < 2; rt++) {
#pragma unroll
      for (int i = 0; i < 4; i++) {
        float rg = fsig(aR[rt][i]);
        float zg = fsig(aZ[rt][i]);
        float nn = ftanh(fmaf(rg, aH[rt][i], aI[rt][i]));
        float hp = h2s[rt][i];
        float hn = fmaxf(fmaf(zg, hp - nn, nn), 0.f);
        h2s[rt][i] = hn;
        const int rr = rt * 16 + kg * 4 + i;
        h2b[nxt][(rr * 128 + d) ^ ((rr & 7) << 3)] = (f16)hn;
      }
    }
    __syncthreads();

    axc[0] = axn[0]; axc[1] = axn[1];
  }

  // ---- epilogue: out[row,col] = h2 . wout[col,:] + bout[col]
  // TS=28 even -> final h2 lives in h2b[0]
  const int orow = tid >> 4;   // 0..31
  const int ocol = tid & 15;   // 0..15, active < 10
  if (ocol < 10) {
    const f16* hb = h2b[0];
    float s = bout[ocol];
#pragma unroll 8
    for (int k = 0; k < 128; k++) {
      float hv = (float)hb[(orow * 128 + k) ^ ((orow & 7) << 3)];
      s = fmaf(hv, wout[ocol * 128 + k], s);
    }
    out[(size_t)(row0 + orow) * 10 + ocol] = s;
  }
}

extern "C" void kernel_launch(void* const* d_in, const int* in_sizes, int n_in,
                              void* d_out, int out_size, void* d_ws, size_t ws_size,
                              hipStream_t stream) {
  const float* x    = (const float*)d_in[0];
  const float* wih1 = (const float*)d_in[1];
  const float* whh1 = (const float*)d_in[2];
  const float* bih1 = (const float*)d_in[3];
  const float* bhh1 = (const float*)d_in[4];
  const float* wih2 = (const float*)d_in[5];
  const float* whh2 = (const float*)d_in[6];
  const float* bih2 = (const float*)d_in[7];
  const float* bhh2 = (const float*)d_in[8];
  const float* wout = (const float*)d_in[9];
  const float* bout = (const float*)d_in[10];
  f16* wsf   = (f16*)d_ws;
  float* out = (float*)d_out;

  prep_weights<<<312, 64, 0, stream>>>(wih1, whh1, wih2, whh2, wsf);
  gru_main<<<NROWS / BR, 512, 0, stream>>>(x, bih1, bhh1, bih2, bhh2,
                                           wout, bout, wsf, out);
}